// Round 23
// baseline (177.474 us; speedup 1.0000x reference)
//
#include <hip/hip_runtime.h>

// Problem constants
#define BB 16
#define CC 128
#define MM 32
#define NN 16384   // H*W

// Workspace layout (float offsets)
#define WS_KV     0        // [16][32][32]
#define WS_KS     16384    // [16][32]
#define WS_SQ     16896    // [16][32]
#define WS_QQ     17408    // [16][32][32]
#define WS_YSUM   33792    // [128]
#define WS_YSQ    33920    // [128]
#define WS_ACCEND 34048    // zeroed region end
#define WS_W2     34304    // [16][128][32]
#define WS_WPACK  99840    // bf16[2][3][32][128] (hi then lo) = 49152 B

typedef __bf16 bf16x8 __attribute__((ext_vector_type(8)));
typedef __bf16 bf16x4 __attribute__((ext_vector_type(4)));
typedef float  f32x16 __attribute__((ext_vector_type(16)));
typedef unsigned short ushort4v __attribute__((ext_vector_type(4)));

union B8 { bf16x8 v8; bf16x4 v4[2]; };

__device__ __forceinline__ float phi_f(float z) {
    return z > 0.f ? z + 1.f : __expf(z);
}

// Raw barrier with LDS-only drain (global ops stay in flight).
__device__ __forceinline__ void lds_barrier() {
    asm volatile("s_waitcnt lgkmcnt(0)" ::: "memory");
    __builtin_amdgcn_sched_barrier(0);
    __builtin_amdgcn_s_barrier();
    __builtin_amdgcn_sched_barrier(0);
}

__device__ __forceinline__ unsigned short bf16bits(float f) {
    const __bf16 h = (__bf16)f;
    return __builtin_bit_cast(unsigned short, h);
}

// ---------------------------------------------------------------------------
__global__ void zero_kernel(float* ws) {
    const int i = blockIdx.x * 256 + threadIdx.x;
    if (i < (WS_ACCEND / 4)) {
        float4 z; z.x = 0.f; z.y = 0.f; z.z = 0.f; z.w = 0.f;
        ((float4*)ws)[i] = z;
    }
}

// ---------------------------------------------------------------------------
// Pack Wq/Wk/Wv rows into bf16 hi/lo fragment buffer (one-time, tiny).
__global__ void wpack_kernel(const float* __restrict__ Wq,
                             const float* __restrict__ Wk,
                             const float* __restrict__ Wv, float* ws) {
    __bf16* wp = (__bf16*)(ws + WS_WPACK);
    const int idx = blockIdx.x * 256 + threadIdx.x;   // 0..12287
    if (idx < 12288) {
        const int mi  = idx >> 12;
        const int rem = idx & 4095;
        const float f = (mi == 0 ? Wq : mi == 1 ? Wk : Wv)[rem];
        const __bf16 h = (__bf16)f;
        wp[idx]         = h;
        wp[12288 + idx] = (__bf16)(f - (float)h);
    }
}

// ---------------------------------------------------------------------------
// ROUND-23: x transpose/pack. Breaks the 64KB-stride HBM-channel aliasing
// (the invariant 0.86 TB/s cap behind 10 null proj rounds): reads x in 1KB
// contiguous wave transactions, writes px-major bf16 xT[n][c] rows (256B
// dense, each 128B line filled by one lane's sequential stores).
// xT lives in d_out channels 32..127 (scratch until out_kernel).
// grid (32 slabs, 16 b) x 256; LDS [128][260] u16 = 65 KB; 2 subtiles/block.
__global__ __launch_bounds__(256) void xpack_kernel(const float* __restrict__ x,
                                                    float* out) {
    __shared__ unsigned short tile[128 * 260];
    const int b = blockIdx.y;
    const int slab = blockIdx.x;          // 512 px each
    const int t = threadIdx.x;
    unsigned short* xT = (unsigned short*)(out + (size_t)b * CC * NN + (size_t)32 * NN);

    for (int st = 0; st < 2; ++st) {
        const int n0 = slab * 512 + st * 256;
        if (st) __syncthreads();   // prev subtile's LDS reads done
        // ---- read: c = cc*4 + wave; lane l reads float4 at px 4l
        // wave transaction = 64 lanes x 16B = 1KB CONTIGUOUS per channel.
        const int l = t & 63;
        #pragma unroll 4
        for (int cc = 0; cc < 32; ++cc) {
            const int c = cc * 4 + (t >> 6);
            const float4 v = ((const float4*)(x + (size_t)b * CC * NN
                                              + (size_t)c * NN + n0))[l];
            ushort4v hv;
            hv[0] = bf16bits(v.x); hv[1] = bf16bits(v.y);
            hv[2] = bf16bits(v.z); hv[3] = bf16bits(v.w);
            *(ushort4v*)&tile[c * 260 + 4 * l] = hv;   // 8B contiguous
        }
        __syncthreads();
        // ---- write: thread t owns px n0+t; row-broadcast LDS reads
        // (fixed c, lanes at consecutive cols: conflict-free), 16B stores.
        uint4* dst = (uint4*)(xT + (size_t)(n0 + t) * 128);
        #pragma unroll
        for (int ci = 0; ci < 16; ++ci) {
            unsigned int u[4];
            #pragma unroll
            for (int q = 0; q < 4; ++q) {
                const unsigned int lo = tile[(ci * 8 + 2 * q) * 260 + t];
                const unsigned int hi = tile[(ci * 8 + 2 * q + 1) * 260 + t];
                u[q] = lo | (hi << 16);
            }
            uint4 vv; vv.x = u[0]; vv.y = u[1]; vv.z = u[2]; vv.w = u[3];
            dst[ci] = vv;
        }
    }
}

// ---------------------------------------------------------------------------
// Projection from packed xT (no X staging at all); KV/Ks by wave 3 via MFMA.
// grid (64,16) x 256 (4 waves); 256 px/block in 8 tiles of 32.
// B-frags: direct 16B-aligned bf16x8 loads from L3-resident xT.
// 2-term W-exact split (Wx ~= Wh*Xh + Wl*Xh, measured-passing 4.77e-7).
// LDS = K/V dbuf only (20 KB). One lds_barrier per tile.
__global__ __launch_bounds__(256) void projmfma_kernel(
    const float* ws_c, float* ws, float* out)
{
    __shared__ __align__(16) char smem[20480];
    __bf16* ktH = (__bf16*)smem;            // [2][1280]
    __bf16* ktL = (__bf16*)(smem + 5120);
    __bf16* vtH = (__bf16*)(smem + 10240);
    __bf16* vtL = (__bf16*)(smem + 15360);

    const int b = blockIdx.y;
    const int t = threadIdx.x;
    const int w = t >> 6;
    const int l = t & 63;
    const int g = l >> 5;
    const int ln31 = l & 31;

    // W fragments from packed buffer (16B vector loads)
    bf16x8 wh[8], wl[8];
    if (w < 3) {
        const __bf16* wp = (const __bf16*)(ws_c + WS_WPACK) + w * 4096 + ln31 * 128;
        #pragma unroll
        for (int kt = 0; kt < 8; ++kt) {
            wh[kt] = *(const bf16x8*)&wp[16 * kt + 8 * g];
            wl[kt] = *(const bf16x8*)&wp[12288 + 16 * kt + 8 * g];
        }
    }

    f32x16 kvA, ksA;
    bf16x8 ones;
    #pragma unroll
    for (int i = 0; i < 16; ++i) { kvA[i] = 0.f; ksA[i] = 0.f; }
    #pragma unroll
    for (int j = 0; j < 8; ++j) ones[j] = (__bf16)1.0f;

    const __bf16* xT = (const __bf16*)((const float*)out + (size_t)b * CC * NN
                                       + (size_t)32 * NN);
    float* qout = out + (size_t)b * CC * NN;
    const int pxbase = blockIdx.x << 8;

    for (int tile = 0; tile < 8; ++tile) {
        const int cur = tile & 1;
        const int n0 = pxbase + (tile << 5);

        if (w < 3) {
            f32x16 acc;
            #pragma unroll
            for (int i = 0; i < 16; ++i) acc[i] = 0.f;
            const __bf16* xp = xT + (size_t)(n0 + ln31) * 128;
            #pragma unroll
            for (int kt = 0; kt < 8; ++kt) {
                const bf16x8 bh = *(const bf16x8*)&xp[16 * kt + 8 * g];
                acc = __builtin_amdgcn_mfma_f32_32x32x16_bf16(wh[kt], bh, acc, 0, 0, 0);
                acc = __builtin_amdgcn_mfma_f32_32x32x16_bf16(wl[kt], bh, acc, 0, 0, 0);
            }
            if (w == 0) {
                float* qp = qout + n0 + ln31;
                #pragma unroll
                for (int i = 0; i < 16; ++i) {
                    const int r = (i & 3) + 8 * (i >> 2) + 4 * g;
                    qp[(size_t)r * NN] = phi_f(acc[i]);
                }
            } else if (w == 1) {
                __bf16* kh = ktH + cur * 1280;
                __bf16* kl = ktL + cur * 1280;
                #pragma unroll
                for (int i = 0; i < 16; ++i) {
                    const int r = (i & 3) + 8 * (i >> 2) + 4 * g;
                    const float f = phi_f(acc[i]);
                    const __bf16 h = (__bf16)f;
                    kh[r * 40 + ln31] = h;
                    kl[r * 40 + ln31] = (__bf16)(f - (float)h);
                }
            } else {
                __bf16* vh = vtH + cur * 1280;
                __bf16* vl = vtL + cur * 1280;
                #pragma unroll
                for (int i = 0; i < 16; ++i) {
                    const int r = (i & 3) + 8 * (i >> 2) + 4 * g;
                    const float f = acc[i];
                    const __bf16 h = (__bf16)f;
                    vh[r * 40 + ln31] = h;
                    vl[r * 40 + ln31] = (__bf16)(f - (float)h);
                }
            }
        } else if (tile > 0) {
            const int pbuf = (cur ^ 1) * 1280;
            const __bf16* khp = ktH + pbuf + ln31 * 40;
            const __bf16* klp = ktL + pbuf + ln31 * 40;
            const __bf16* vhp = vtH + pbuf + ln31 * 40;
            const __bf16* vlp = vtL + pbuf + ln31 * 40;
            #pragma unroll
            for (int s = 0; s < 2; ++s) {
                const int k0 = s * 16 + g * 8;
                const bf16x8 akh = *(const bf16x8*)&khp[k0];
                const bf16x8 akl = *(const bf16x8*)&klp[k0];
                const bf16x8 bvh = *(const bf16x8*)&vhp[k0];
                const bf16x8 bvl = *(const bf16x8*)&vlp[k0];
                kvA = __builtin_amdgcn_mfma_f32_32x32x16_bf16(akh, bvh, kvA, 0, 0, 0);
                kvA = __builtin_amdgcn_mfma_f32_32x32x16_bf16(akh, bvl, kvA, 0, 0, 0);
                kvA = __builtin_amdgcn_mfma_f32_32x32x16_bf16(akl, bvh, kvA, 0, 0, 0);
                ksA = __builtin_amdgcn_mfma_f32_32x32x16_bf16(akh, ones, ksA, 0, 0, 0);
                ksA = __builtin_amdgcn_mfma_f32_32x32x16_bf16(akl, ones, ksA, 0, 0, 0);
            }
        }
        lds_barrier();
    }

    // epilogue (wave 3): tile 7 lives in buffer 1 (7&1); last barrier ordered it
    if (w == 3) {
        const int pbuf = 1280;
        const __bf16* khp = ktH + pbuf + ln31 * 40;
        const __bf16* klp = ktL + pbuf + ln31 * 40;
        const __bf16* vhp = vtH + pbuf + ln31 * 40;
        const __bf16* vlp = vtL + pbuf + ln31 * 40;
        #pragma unroll
        for (int s = 0; s < 2; ++s) {
            const int k0 = s * 16 + g * 8;
            const bf16x8 akh = *(const bf16x8*)&khp[k0];
            const bf16x8 akl = *(const bf16x8*)&klp[k0];
            const bf16x8 bvh = *(const bf16x8*)&vhp[k0];
            const bf16x8 bvl = *(const bf16x8*)&vlp[k0];
            kvA = __builtin_amdgcn_mfma_f32_32x32x16_bf16(akh, bvh, kvA, 0, 0, 0);
            kvA = __builtin_amdgcn_mfma_f32_32x32x16_bf16(akh, bvl, kvA, 0, 0, 0);
            kvA = __builtin_amdgcn_mfma_f32_32x32x16_bf16(akl, bvh, kvA, 0, 0, 0);
            ksA = __builtin_amdgcn_mfma_f32_32x32x16_bf16(akh, ones, ksA, 0, 0, 0);
            ksA = __builtin_amdgcn_mfma_f32_32x32x16_bf16(akl, ones, ksA, 0, 0, 0);
        }
        float* kvb = ws + WS_KV + (b << 10);
        #pragma unroll
        for (int i = 0; i < 16; ++i) {
            const int r = (i & 3) + 8 * (i >> 2) + 4 * g;
            atomicAdd(&kvb[r * 32 + ln31], kvA[i]);
        }
        if (ln31 == 0) {
            #pragma unroll
            for (int i = 0; i < 16; ++i) {
                const int r = (i & 3) + 8 * (i >> 2) + 4 * g;
                atomicAdd(&ws[WS_KS + (b << 5) + r], ksA[i]);
            }
        }
    }
}

// ---------------------------------------------------------------------------
// Pass C via MFMA (unchanged).  grid (64,16) x 256.
__global__ __launch_bounds__(256) void qq_kernel(const float* qsrc, float* ws) {
    __shared__ __align__(16) char qsm[33792];
    __bf16* Qh = (__bf16*)qsm;              // [32][264]
    __bf16* Ql = (__bf16*)(qsm + 16896);    // [32][264]
    float*  red   = (float*)qsm;
    float*  sqred = (float*)(qsm + 17408);

    const int b = blockIdx.y;
    const int t = threadIdx.x;
    const int w = t >> 6;
    const int l = t & 63;
    const int g = l >> 5;
    const int ln31 = l & 31;

    const float* ksb = ws + WS_KS + (b << 5);
    const int n = (blockIdx.x << 8) + t;
    const float* qp = qsrc + (size_t)b * CC * NN + n;

    float qa[32];
    #pragma unroll
    for (int m = 0; m < 32; ++m) qa[m] = qp[(size_t)m * NN];

    float denom = 1e-6f;
    #pragma unroll
    for (int m = 0; m < 32; ++m) denom = fmaf(qa[m], ksb[m], denom);
    const float inv = 1.0f / (16384.0f * denom);
    #pragma unroll
    for (int m = 0; m < 32; ++m) qa[m] *= inv;

    #pragma unroll
    for (int m = 0; m < 32; ++m) {
        const __bf16 h = (__bf16)qa[m];
        Qh[m * 264 + t] = h;
        Ql[m * 264 + t] = (__bf16)(qa[m] - (float)h);
    }
    __syncthreads();

    f32x16 qqA, sqA;
    bf16x8 ones;
    #pragma unroll
    for (int i = 0; i < 16; ++i) { qqA[i] = 0.f; sqA[i] = 0.f; }
    #pragma unroll
    for (int j = 0; j < 8; ++j) ones[j] = (__bf16)1.0f;

    #pragma unroll
    for (int sub = 0; sub < 2; ++sub) {
        #pragma unroll
        for (int s = 0; s < 2; ++s) {
            const int k0 = (w << 6) + (sub << 5) + s * 16 + g * 8;
            const bf16x8 ah = *(const bf16x8*)&Qh[ln31 * 264 + k0];
            const bf16x8 al = *(const bf16x8*)&Ql[ln31 * 264 + k0];
            qqA = __builtin_amdgcn_mfma_f32_32x32x16_bf16(ah, ah, qqA, 0, 0, 0);
            qqA = __builtin_amdgcn_mfma_f32_32x32x16_bf16(ah, al, qqA, 0, 0, 0);
            qqA = __builtin_amdgcn_mfma_f32_32x32x16_bf16(al, ah, qqA, 0, 0, 0);
            sqA = __builtin_amdgcn_mfma_f32_32x32x16_bf16(ah, ones, sqA, 0, 0, 0);
            sqA = __builtin_amdgcn_mfma_f32_32x32x16_bf16(al, ones, sqA, 0, 0, 0);
        }
    }
    __syncthreads();

    #pragma unroll
    for (int i = 0; i < 16; ++i) red[t * 17 + i] = qqA[i];
    if (ln31 == 0) {
        #pragma unroll
        for (int i = 0; i < 16; ++i) {
            const int r = (i & 3) + 8 * (i >> 2) + 4 * g;
            sqred[(w << 5) + r] = sqA[i];
        }
    }
    __syncthreads();
    if (t < 64) {
        float* qqb = ws + WS_QQ + (b << 10);
        #pragma unroll
        for (int i = 0; i < 16; ++i) {
            const int r = (i & 3) + 8 * (i >> 2) + 4 * g;
            const float s = red[t*17+i] + red[(t+64)*17+i] + red[(t+128)*17+i] + red[(t+192)*17+i];
            atomicAdd(&qqb[r * 32 + ln31], s);
        }
    }
    if (t < 32) {
        const float s = sqred[t] + sqred[32 + t] + sqred[64 + t] + sqred[96 + t];
        atomicAdd(&ws[WS_SQ + (b << 5) + t], s);
    }
}

// ---------------------------------------------------------------------------
// Merged W2 + BN stats (unchanged).
__global__ __launch_bounds__(128) void bnstat_kernel(const float* __restrict__ Wout,
                                                     float* ws) {
    const int b = blockIdx.x;
    const int c = threadIdx.x;
    const float* kvb = ws + WS_KV + (b << 10);
    const float* wo  = Wout + (c << 5);
    float w[32];
    #pragma unroll
    for (int v = 0; v < 32; ++v) w[v] = 0.f;
    for (int m = 0; m < 32; ++m) {
        const float wm = wo[m];
        #pragma unroll
        for (int v = 0; v < 32; ++v) w[v] = fmaf(wm, kvb[(m << 5) + v], w[v]);
    }
    float* w2b = ws + WS_W2 + (b << 12) + (c << 5);
    #pragma unroll
    for (int v = 0; v < 32; ++v) w2b[v] = w[v];

    const float* sq = ws + WS_SQ + (b << 5);
    const float* qq = ws + WS_QQ + (b << 10);
    float mb = 0.f;
    #pragma unroll
    for (int v = 0; v < 32; ++v) mb = fmaf(w[v], sq[v], mb);
    float qf = 0.f;
    for (int u = 0; u < 32; ++u) {
        float tacc = 0.f;
        #pragma unroll
        for (int v = 0; v < 32; ++v) tacc = fmaf(qq[(u << 5) + v], w[v], tacc);
        qf = fmaf(w[u], tacc, qf);
    }
    atomicAdd(&ws[WS_YSUM + c], mb);
    atomicAdd(&ws[WS_YSQ + c], qf);
}

// ---------------------------------------------------------------------------
// Output via MFMA with inline BN finalize (unchanged).
__global__ __launch_bounds__(256) void out_kernel(const float* qsrc, const float* ws,
                                                  const float* __restrict__ gamma,
                                                  const float* __restrict__ beta,
                                                  float* out) {
    __shared__ __align__(16) __bf16 Qh[256 * 36];
    __shared__ __align__(16) __bf16 Ql[256 * 36];
    __shared__ float scs[CC];
    __shared__ float bis[CC];

    const int b = blockIdx.y;
    const int t = threadIdx.x;
    const int w = t >> 6;
    const int l = t & 63;
    const int g = l >> 5;
    const int ln31 = l & 31;

    if (t < CC) {
        const float invBN = 1.0f / 262144.0f;
        const float mean = ws[WS_YSUM + t] * invBN;
        const float var  = ws[WS_YSQ + t] * invBN - mean * mean;
        const float s = gamma[t] * rsqrtf(var + 1e-5f);
        scs[t] = s;
        bis[t] = fmaf(-mean, s, beta[t]);
    }

    const int n = (blockIdx.x << 8) + t;
    const float* ksb = ws + WS_KS + (b << 5);

    const float* qp = qsrc + (size_t)b * CC * NN + n;
    float qa[32];
    #pragma unroll
    for (int m = 0; m < 32; ++m) qa[m] = qp[(size_t)m * NN];

    float d0 = 1e-6f;
    #pragma unroll
    for (int m = 0; m < 32; ++m) d0 = fmaf(qa[m], ksb[m], d0);
    const float inv = 1.0f / (16384.0f * d0);
    #pragma unroll
    for (int m = 0; m < 32; ++m) qa[m] *= inv;

    {
        __bf16 qh[32], ql[32];
        #pragma unroll
        for (int m = 0; m < 32; ++m) {
            const __bf16 h = (__bf16)qa[m];
            qh[m] = h;
            ql[m] = (__bf16)(qa[m] - (float)h);
        }
        #pragma unroll
        for (int i = 0; i < 8; ++i) {
            *(bf16x4*)&Qh[t * 36 + i * 4] = *(bf16x4*)&qh[i * 4];
            *(bf16x4*)&Ql[t * 36 + i * 4] = *(bf16x4*)&ql[i * 4];
        }
    }
    __syncthreads();

    const float* w2b = ws + WS_W2 + (b << 12);
    float* ob = out + (size_t)b * CC * NN + (blockIdx.x << 8);

    #pragma unroll
    for (int cb = 0; cb < 4; ++cb) {
        bf16x8 ah[2], al[2];
        #pragma unroll
        for (int kt = 0; kt < 2; ++kt) {
            const float* wp = w2b + (cb * 32 + ln31) * 32 + kt * 16 + g * 8;
            #pragma unroll
            for (int j = 0; j < 8; ++j) {
                const float f = wp[j];
                const __bf16 h = (__bf16)f;
                ah[kt][j] = h;
                al[kt][j] = (__bf16)(f - (float)h);
            }
        }
        #pragma unroll
        for (int pg = 0; pg < 2; ++pg) {
            const int px0 = (w << 6) + (pg << 5);
            f32x16 acc;
            #pragma unroll
            for (int i = 0; i < 16; ++i) acc[i] = 0.f;
            #pragma unroll
            for (int kt = 0; kt < 2; ++kt) {
                const int k0 = kt * 16 + g * 8;
                const __bf16* qhp = &Qh[(px0 + ln31) * 36 + k0];
                const __bf16* qlp = &Ql[(px0 + ln31) * 36 + k0];
                B8 bh, bl;
                bh.v4[0] = *(const bf16x4*)&qhp[0];
                bh.v4[1] = *(const bf16x4*)&qhp[4];
                bl.v4[0] = *(const bf16x4*)&qlp[0];
                bl.v4[1] = *(const bf16x4*)&qlp[4];
                acc = __builtin_amdgcn_mfma_f32_32x32x16_bf16(ah[kt], bh.v8, acc, 0, 0, 0);
                acc = __builtin_amdgcn_mfma_f32_32x32x16_bf16(ah[kt], bl.v8, acc, 0, 0, 0);
                acc = __builtin_amdgcn_mfma_f32_32x32x16_bf16(al[kt], bh.v8, acc, 0, 0, 0);
            }
            #pragma unroll
            for (int i = 0; i < 16; ++i) {
                const int r = (i & 3) + 8 * (i >> 2) + 4 * g;
                const int c = cb * 32 + r;
                const float v = fmaf(scs[c], acc[i], bis[c]);
                __builtin_nontemporal_store(v, &ob[(size_t)c * NN + px0 + ln31]);
            }
        }
    }
}

// ---------------------------------------------------------------------------
extern "C" void kernel_launch(void* const* d_in, const int* in_sizes, int n_in,
                              void* d_out, int out_size, void* d_ws, size_t ws_size,
                              hipStream_t stream) {
    const float* x     = (const float*)d_in[0];
    const float* Wq    = (const float*)d_in[1];
    const float* Wk    = (const float*)d_in[2];
    const float* Wv    = (const float*)d_in[3];
    const float* Wout  = (const float*)d_in[4];
    const float* gamma = (const float*)d_in[5];
    const float* beta  = (const float*)d_in[6];
    float* ws  = (float*)d_ws;
    float* out = (float*)d_out;

    zero_kernel<<<34, 256, 0, stream>>>(ws);
    wpack_kernel<<<48, 256, 0, stream>>>(Wq, Wk, Wv, ws);
    xpack_kernel<<<dim3(32, 16), 256, 0, stream>>>(x, out);
    projmfma_kernel<<<dim3(64, 16), 256, 0, stream>>>(ws, ws, out);
    qq_kernel<<<dim3(64, 16), 256, 0, stream>>>(out, ws);
    bnstat_kernel<<<16, 128, 0, stream>>>(Wout, ws);
    out_kernel<<<dim3(64, 16), 256, 0, stream>>>(out, ws, gamma, beta, out);
}

// Round 24
// 108.663 us; speedup vs baseline: 1.6332x; 1.6332x over previous
//
#include <hip/hip_runtime.h>

// Problem constants
#define BB 16
#define CC 128
#define MM 32
#define NN 16384   // H*W

// Workspace layout (float offsets)
#define WS_KV     0        // [16][32][32]
#define WS_KS     16384    // [16][32]
#define WS_SQ     16896    // [16][32]
#define WS_QQ     17408    // [16][32][32]
#define WS_YSUM   33792    // [128]
#define WS_YSQ    33920    // [128]
#define WS_ACCEND 34048    // zeroed region end
#define WS_W2     34304    // [16][128][32]

typedef __bf16 bf16x8 __attribute__((ext_vector_type(8)));
typedef __bf16 bf16x4 __attribute__((ext_vector_type(4)));
typedef float  f32x16 __attribute__((ext_vector_type(16)));

union B8 { bf16x8 v8; bf16x4 v4[2]; };

__device__ __forceinline__ float phi_f(float z) {
    // elu(z) + 1 (alpha=1): z>0 -> z+1 ; z<=0 -> exp(z)
    return z > 0.f ? z + 1.f : __expf(z);
}

// Raw barrier with LDS-only drain (global ops stay in flight).
__device__ __forceinline__ void lds_barrier() {
    asm volatile("s_waitcnt lgkmcnt(0)" ::: "memory");
    __builtin_amdgcn_sched_barrier(0);
    __builtin_amdgcn_s_barrier();
    __builtin_amdgcn_sched_barrier(0);
}

// ---------------------------------------------------------------------------
// Zero the ws accumulator region.
__global__ void zero_kernel(float* ws) {
    const int i = blockIdx.x * 256 + threadIdx.x;
    if (i < (WS_ACCEND / 4)) {
        float4 z; z.x = 0.f; z.y = 0.f; z.z = 0.f; z.w = 0.f;
        ((float4*)ws)[i] = z;
    }
}

// ---------------------------------------------------------------------------
// Fused projection; KV/Ks accumulated by WAVE 3 via MFMA.  (round-21 best:
// 112.86 us total.)  64-px tiles -> 8 rounds/block; X hi-only (W-exact
// 2-term split: Wx ~= Wh*Xh + Wl*Xh, rel err ~2^-9); LDS 70 KB -> 2
// blocks/CU.  Waves 0-2: 2 acc groups (px 0-31 / 32-63), 32 MFMA/tile;
// wave 3: KV/Ks MFMA of PREVIOUS tile (4 k-slices); w1/w2 write K/V
// transposed [m][px] bf16 hi/lo (stride 72).
__global__ __launch_bounds__(256) void projmfma_kernel(
    const float* __restrict__ x,
    const float* __restrict__ Wq, const float* __restrict__ Wk,
    const float* __restrict__ Wv,
    float* ws, float* __restrict__ qout)
{
    __shared__ __align__(16) char smem[71680];
    __bf16* Xh  = (__bf16*)smem;                    // [2][64*136] = 34816 B
    __bf16* ktH = (__bf16*)(smem + 34816);          // [2][32*72]  = 9216 B
    __bf16* ktL = (__bf16*)(smem + 44032);
    __bf16* vtH = (__bf16*)(smem + 53248);
    __bf16* vtL = (__bf16*)(smem + 62464);

    const int b = blockIdx.y;
    const int t = threadIdx.x;
    const int w = t >> 6;          // wave id
    const int l = t & 63;
    const int g = l >> 5;          // k-group within wave (0/1)
    const int ln31 = l & 31;       // A row / B col / D col

    // ---- W fragments (waves 0..2): exact split W = Wh + Wl
    bf16x8 wh[8], wl[8];
    if (w < 3) {
        const float* Wm = (w == 0) ? Wq : (w == 1) ? Wk : Wv;
        const float* wr = Wm + ln31 * CC;
        #pragma unroll
        for (int kt = 0; kt < 8; ++kt) {
            const int k0 = 16 * kt + 8 * g;
            #pragma unroll
            for (int j = 0; j < 8; ++j) {
                const float f = wr[k0 + j];
                const __bf16 h = (__bf16)f;
                wh[kt][j] = h;
                wl[kt][j] = (__bf16)(f - (float)h);
            }
        }
    }

    f32x16 kvA, ksA;
    bf16x8 ones;
    #pragma unroll
    for (int i = 0; i < 16; ++i) { kvA[i] = 0.f; ksA[i] = 0.f; }
    #pragma unroll
    for (int j = 0; j < 8; ++j) ones[j] = (__bf16)1.0f;

    // staging: thread t -> pixel px (0..63), channel block cb (32 ch)
    const int px = t & 63;
    const int cb = t >> 6;        // 0..3

    const float* xbase = x + (size_t)b * CC * NN + (blockIdx.x << 9) + px;

    for (int tile = 0; tile < 8; ++tile) {
        const int cur = tile & 1;
        const int n0 = (blockIdx.x << 9) + (tile << 6);

        // ---- stage 64-px tile into Xh[cur] (hi only)
        {
            const float* xp = xbase + (tile << 6);
            float xb[32];
            #pragma unroll
            for (int j = 0; j < 32; ++j)
                xb[j] = xp[(size_t)(cb * 32 + j) * NN];
            __bf16 hb[32];
            #pragma unroll
            for (int j = 0; j < 32; ++j) hb[j] = (__bf16)xb[j];
            #pragma unroll
            for (int q = 0; q < 4; ++q)
                *(bf16x8*)&Xh[cur * 8704 + px * 136 + cb * 32 + q * 8] =
                    *(bf16x8*)&hb[q * 8];
        }
        lds_barrier();

        // ---- MFMA phase
        if (w < 3) {
            f32x16 a0, a1;
            #pragma unroll
            for (int i = 0; i < 16; ++i) { a0[i] = 0.f; a1[i] = 0.f; }
            const __bf16* xh = Xh + cur * 8704;
            #pragma unroll
            for (int kt = 0; kt < 8; ++kt) {
                const int k0 = 16 * kt + 8 * g;
                const bf16x8 b0 = *(const bf16x8*)&xh[ln31 * 136 + k0];
                const bf16x8 b1 = *(const bf16x8*)&xh[(ln31 + 32) * 136 + k0];
                a0 = __builtin_amdgcn_mfma_f32_32x32x16_bf16(wh[kt], b0, a0, 0, 0, 0);
                a0 = __builtin_amdgcn_mfma_f32_32x32x16_bf16(wl[kt], b0, a0, 0, 0, 0);
                a1 = __builtin_amdgcn_mfma_f32_32x32x16_bf16(wh[kt], b1, a1, 0, 0, 0);
                a1 = __builtin_amdgcn_mfma_f32_32x32x16_bf16(wl[kt], b1, a1, 0, 0, 0);
            }
            if (w == 0) {
                float* qp = qout + (size_t)b * CC * NN + n0 + ln31;
                #pragma unroll
                for (int i = 0; i < 16; ++i) {
                    const int r = (i & 3) + 8 * (i >> 2) + 4 * g;
                    qp[(size_t)r * NN]      = phi_f(a0[i]);
                    qp[(size_t)r * NN + 32] = phi_f(a1[i]);
                }
            } else if (w == 1) {
                __bf16* kh = ktH + cur * 2304;
                __bf16* kl = ktL + cur * 2304;
                #pragma unroll
                for (int i = 0; i < 16; ++i) {
                    const int r = (i & 3) + 8 * (i >> 2) + 4 * g;
                    const float f0 = phi_f(a0[i]);
                    const float f1 = phi_f(a1[i]);
                    const __bf16 h0 = (__bf16)f0;
                    const __bf16 h1 = (__bf16)f1;
                    kh[r * 72 + ln31]      = h0;
                    kl[r * 72 + ln31]      = (__bf16)(f0 - (float)h0);
                    kh[r * 72 + 32 + ln31] = h1;
                    kl[r * 72 + 32 + ln31] = (__bf16)(f1 - (float)h1);
                }
            } else {
                __bf16* vh = vtH + cur * 2304;
                __bf16* vl = vtL + cur * 2304;
                #pragma unroll
                for (int i = 0; i < 16; ++i) {
                    const int r = (i & 3) + 8 * (i >> 2) + 4 * g;
                    const float f0 = a0[i];
                    const float f1 = a1[i];
                    const __bf16 h0 = (__bf16)f0;
                    const __bf16 h1 = (__bf16)f1;
                    vh[r * 72 + ln31]      = h0;
                    vl[r * 72 + ln31]      = (__bf16)(f0 - (float)h0);
                    vh[r * 72 + 32 + ln31] = h1;
                    vl[r * 72 + 32 + ln31] = (__bf16)(f1 - (float)h1);
                }
            }
        } else if (tile > 0) {
            const int pb = (cur ^ 1) * 2304;
            const __bf16* khp = ktH + pb + ln31 * 72;
            const __bf16* klp = ktL + pb + ln31 * 72;
            const __bf16* vhp = vtH + pb + ln31 * 72;
            const __bf16* vlp = vtL + pb + ln31 * 72;
            #pragma unroll
            for (int s = 0; s < 4; ++s) {
                const int k0 = s * 16 + g * 8;
                const bf16x8 akh = *(const bf16x8*)&khp[k0];
                const bf16x8 akl = *(const bf16x8*)&klp[k0];
                const bf16x8 bvh = *(const bf16x8*)&vhp[k0];
                const bf16x8 bvl = *(const bf16x8*)&vlp[k0];
                kvA = __builtin_amdgcn_mfma_f32_32x32x16_bf16(akh, bvh, kvA, 0, 0, 0);
                kvA = __builtin_amdgcn_mfma_f32_32x32x16_bf16(akh, bvl, kvA, 0, 0, 0);
                kvA = __builtin_amdgcn_mfma_f32_32x32x16_bf16(akl, bvh, kvA, 0, 0, 0);
                ksA = __builtin_amdgcn_mfma_f32_32x32x16_bf16(akh, ones, ksA, 0, 0, 0);
                ksA = __builtin_amdgcn_mfma_f32_32x32x16_bf16(akl, ones, ksA, 0, 0, 0);
            }
        }
        lds_barrier();
    }

    // ---- epilogue (wave 3): KV/Ks for tile 7 (buffer 1), then atomics
    if (w == 3) {
        const int pb = 2304;
        const __bf16* khp = ktH + pb + ln31 * 72;
        const __bf16* klp = ktL + pb + ln31 * 72;
        const __bf16* vhp = vtH + pb + ln31 * 72;
        const __bf16* vlp = vtL + pb + ln31 * 72;
        #pragma unroll
        for (int s = 0; s < 4; ++s) {
            const int k0 = s * 16 + g * 8;
            const bf16x8 akh = *(const bf16x8*)&khp[k0];
            const bf16x8 akl = *(const bf16x8*)&klp[k0];
            const bf16x8 bvh = *(const bf16x8*)&vhp[k0];
            const bf16x8 bvl = *(const bf16x8*)&vlp[k0];
            kvA = __builtin_amdgcn_mfma_f32_32x32x16_bf16(akh, bvh, kvA, 0, 0, 0);
            kvA = __builtin_amdgcn_mfma_f32_32x32x16_bf16(akh, bvl, kvA, 0, 0, 0);
            kvA = __builtin_amdgcn_mfma_f32_32x32x16_bf16(akl, bvh, kvA, 0, 0, 0);
            ksA = __builtin_amdgcn_mfma_f32_32x32x16_bf16(akh, ones, ksA, 0, 0, 0);
            ksA = __builtin_amdgcn_mfma_f32_32x32x16_bf16(akl, ones, ksA, 0, 0, 0);
        }
        float* kvb = ws + WS_KV + (b << 10);
        #pragma unroll
        for (int i = 0; i < 16; ++i) {
            const int r = (i & 3) + 8 * (i >> 2) + 4 * g;
            atomicAdd(&kvb[r * 32 + ln31], kvA[i]);
        }
        if (ln31 == 0) {
            #pragma unroll
            for (int i = 0; i < 16; ++i) {
                const int r = (i & 3) + 8 * (i >> 2) + 4 * g;
                atomicAdd(&ws[WS_KS + (b << 5) + r], ksA[i]);
            }
        }
    }
}

// ---------------------------------------------------------------------------
// Pass C via MFMA: stage Q' transposed [m][px] bf16 hi/lo; each wave MFMAs
// its own 64 px (QQ 3-term symmetric split; Sq via ones).  grid (64,16) x 256.
__global__ __launch_bounds__(256) void qq_kernel(const float* qsrc, float* ws) {
    __shared__ __align__(16) char qsm[33792];
    __bf16* Qh = (__bf16*)qsm;              // [32][264]
    __bf16* Ql = (__bf16*)(qsm + 16896);    // [32][264]
    float*  red   = (float*)qsm;            // [256*17] epilogue overlay
    float*  sqred = (float*)(qsm + 17408);  // [128]    epilogue overlay

    const int b = blockIdx.y;
    const int t = threadIdx.x;
    const int w = t >> 6;
    const int l = t & 63;
    const int g = l >> 5;
    const int ln31 = l & 31;

    const float* ksb = ws + WS_KS + (b << 5);
    const int n = (blockIdx.x << 8) + t;
    const float* qp = qsrc + (size_t)b * CC * NN + n;

    float qa[32];
    #pragma unroll
    for (int m = 0; m < 32; ++m) qa[m] = qp[(size_t)m * NN];

    float denom = 1e-6f;
    #pragma unroll
    for (int m = 0; m < 32; ++m) denom = fmaf(qa[m], ksb[m], denom);
    const float inv = 1.0f / (16384.0f * denom);
    #pragma unroll
    for (int m = 0; m < 32; ++m) qa[m] *= inv;

    #pragma unroll
    for (int m = 0; m < 32; ++m) {
        const __bf16 h = (__bf16)qa[m];
        Qh[m * 264 + t] = h;
        Ql[m * 264 + t] = (__bf16)(qa[m] - (float)h);
    }
    __syncthreads();

    f32x16 qqA, sqA;
    bf16x8 ones;
    #pragma unroll
    for (int i = 0; i < 16; ++i) { qqA[i] = 0.f; sqA[i] = 0.f; }
    #pragma unroll
    for (int j = 0; j < 8; ++j) ones[j] = (__bf16)1.0f;

    #pragma unroll
    for (int sub = 0; sub < 2; ++sub) {
        #pragma unroll
        for (int s = 0; s < 2; ++s) {
            const int k0 = (w << 6) + (sub << 5) + s * 16 + g * 8;
            const bf16x8 ah = *(const bf16x8*)&Qh[ln31 * 264 + k0];
            const bf16x8 al = *(const bf16x8*)&Ql[ln31 * 264 + k0];
            qqA = __builtin_amdgcn_mfma_f32_32x32x16_bf16(ah, ah, qqA, 0, 0, 0);
            qqA = __builtin_amdgcn_mfma_f32_32x32x16_bf16(ah, al, qqA, 0, 0, 0);
            qqA = __builtin_amdgcn_mfma_f32_32x32x16_bf16(al, ah, qqA, 0, 0, 0);
            sqA = __builtin_amdgcn_mfma_f32_32x32x16_bf16(ah, ones, sqA, 0, 0, 0);
            sqA = __builtin_amdgcn_mfma_f32_32x32x16_bf16(al, ones, sqA, 0, 0, 0);
        }
    }
    __syncthreads();

    #pragma unroll
    for (int i = 0; i < 16; ++i) red[t * 17 + i] = qqA[i];
    if (ln31 == 0) {
        #pragma unroll
        for (int i = 0; i < 16; ++i) {
            const int r = (i & 3) + 8 * (i >> 2) + 4 * g;
            sqred[(w << 5) + r] = sqA[i];
        }
    }
    __syncthreads();
    if (t < 64) {
        float* qqb = ws + WS_QQ + (b << 10);
        #pragma unroll
        for (int i = 0; i < 16; ++i) {
            const int r = (i & 3) + 8 * (i >> 2) + 4 * g;
            const float s = red[t*17+i] + red[(t+64)*17+i] + red[(t+128)*17+i] + red[(t+192)*17+i];
            atomicAdd(&qqb[r * 32 + ln31], s);
        }
    }
    if (t < 32) {
        const float s = sqred[t] + sqred[32 + t] + sqred[64 + t] + sqred[96 + t];
        atomicAdd(&ws[WS_SQ + (b << 5) + t], s);
    }
}

// ---------------------------------------------------------------------------
// Merged W2 + BN stats.
__global__ __launch_bounds__(128) void bnstat_kernel(const float* __restrict__ Wout,
                                                     float* ws) {
    const int b = blockIdx.x;
    const int c = threadIdx.x;
    const float* kvb = ws + WS_KV + (b << 10);
    const float* wo  = Wout + (c << 5);
    float w[32];
    #pragma unroll
    for (int v = 0; v < 32; ++v) w[v] = 0.f;
    for (int m = 0; m < 32; ++m) {
        const float wm = wo[m];
        #pragma unroll
        for (int v = 0; v < 32; ++v) w[v] = fmaf(wm, kvb[(m << 5) + v], w[v]);
    }
    float* w2b = ws + WS_W2 + (b << 12) + (c << 5);
    #pragma unroll
    for (int v = 0; v < 32; ++v) w2b[v] = w[v];

    const float* sq = ws + WS_SQ + (b << 5);
    const float* qq = ws + WS_QQ + (b << 10);
    float mb = 0.f;
    #pragma unroll
    for (int v = 0; v < 32; ++v) mb = fmaf(w[v], sq[v], mb);
    float qf = 0.f;
    for (int u = 0; u < 32; ++u) {
        float tacc = 0.f;
        #pragma unroll
        for (int v = 0; v < 32; ++v) tacc = fmaf(qq[(u << 5) + v], w[v], tacc);
        qf = fmaf(w[u], tacc, qf);
    }
    atomicAdd(&ws[WS_YSUM + c], mb);
    atomicAdd(&ws[WS_YSQ + c], qf);
}

// ---------------------------------------------------------------------------
// Output via MFMA with inline BN finalize: y = scale_c*(W2[c]·Q'_n) + bias_c.
__global__ __launch_bounds__(256) void out_kernel(const float* qsrc, const float* ws,
                                                  const float* __restrict__ gamma,
                                                  const float* __restrict__ beta,
                                                  float* out) {
    __shared__ __align__(16) __bf16 Qh[256 * 36];
    __shared__ __align__(16) __bf16 Ql[256 * 36];
    __shared__ float scs[CC];
    __shared__ float bis[CC];

    const int b = blockIdx.y;
    const int t = threadIdx.x;
    const int w = t >> 6;
    const int l = t & 63;
    const int g = l >> 5;
    const int ln31 = l & 31;

    if (t < CC) {
        const float invBN = 1.0f / 262144.0f;
        const float mean = ws[WS_YSUM + t] * invBN;
        const float var  = ws[WS_YSQ + t] * invBN - mean * mean;
        const float s = gamma[t] * rsqrtf(var + 1e-5f);
        scs[t] = s;
        bis[t] = fmaf(-mean, s, beta[t]);
    }

    const int n = (blockIdx.x << 8) + t;
    const float* ksb = ws + WS_KS + (b << 5);

    const float* qp = qsrc + (size_t)b * CC * NN + n;
    float qa[32];
    #pragma unroll
    for (int m = 0; m < 32; ++m) qa[m] = qp[(size_t)m * NN];

    float d0 = 1e-6f;
    #pragma unroll
    for (int m = 0; m < 32; ++m) d0 = fmaf(qa[m], ksb[m], d0);
    const float inv = 1.0f / (16384.0f * d0);
    #pragma unroll
    for (int m = 0; m < 32; ++m) qa[m] *= inv;

    {
        __bf16 qh[32], ql[32];
        #pragma unroll
        for (int m = 0; m < 32; ++m) {
            const __bf16 h = (__bf16)qa[m];
            qh[m] = h;
            ql[m] = (__bf16)(qa[m] - (float)h);
        }
        #pragma unroll
        for (int i = 0; i < 8; ++i) {
            *(bf16x4*)&Qh[t * 36 + i * 4] = *(bf16x4*)&qh[i * 4];
            *(bf16x4*)&Ql[t * 36 + i * 4] = *(bf16x4*)&ql[i * 4];
        }
    }
    __syncthreads();

    const float* w2b = ws + WS_W2 + (b << 12);
    float* ob = out + (size_t)b * CC * NN + (blockIdx.x << 8);

    #pragma unroll
    for (int cb = 0; cb < 4; ++cb) {
        bf16x8 ah[2], al[2];
        #pragma unroll
        for (int kt = 0; kt < 2; ++kt) {
            const float* wp = w2b + (cb * 32 + ln31) * 32 + kt * 16 + g * 8;
            #pragma unroll
            for (int j = 0; j < 8; ++j) {
                const float f = wp[j];
                const __bf16 h = (__bf16)f;
                ah[kt][j] = h;
                al[kt][j] = (__bf16)(f - (float)h);
            }
        }
        #pragma unroll
        for (int pg = 0; pg < 2; ++pg) {
            const int px0 = (w << 6) + (pg << 5);
            f32x16 acc;
            #pragma unroll
            for (int i = 0; i < 16; ++i) acc[i] = 0.f;
            #pragma unroll
            for (int kt = 0; kt < 2; ++kt) {
                const int k0 = kt * 16 + g * 8;
                const __bf16* qhp = &Qh[(px0 + ln31) * 36 + k0];
                const __bf16* qlp = &Ql[(px0 + ln31) * 36 + k0];
                B8 bh, bl;
                bh.v4[0] = *(const bf16x4*)&qhp[0];
                bh.v4[1] = *(const bf16x4*)&qhp[4];
                bl.v4[0] = *(const bf16x4*)&qlp[0];
                bl.v4[1] = *(const bf16x4*)&qlp[4];
                acc = __builtin_amdgcn_mfma_f32_32x32x16_bf16(ah[kt], bh.v8, acc, 0, 0, 0);
                acc = __builtin_amdgcn_mfma_f32_32x32x16_bf16(ah[kt], bl.v8, acc, 0, 0, 0);
                acc = __builtin_amdgcn_mfma_f32_32x32x16_bf16(al[kt], bh.v8, acc, 0, 0, 0);
            }
            #pragma unroll
            for (int i = 0; i < 16; ++i) {
                const int r = (i & 3) + 8 * (i >> 2) + 4 * g;
                const int c = cb * 32 + r;
                const float v = fmaf(scs[c], acc[i], bis[c]);
                __builtin_nontemporal_store(v, &ob[(size_t)c * NN + px0 + ln31]);
            }
        }
    }
}

// ---------------------------------------------------------------------------
extern "C" void kernel_launch(void* const* d_in, const int* in_sizes, int n_in,
                              void* d_out, int out_size, void* d_ws, size_t ws_size,
                              hipStream_t stream) {
    const float* x     = (const float*)d_in[0];
    const float* Wq    = (const float*)d_in[1];
    const float* Wk    = (const float*)d_in[2];
    const float* Wv    = (const float*)d_in[3];
    const float* Wout  = (const float*)d_in[4];
    const float* gamma = (const float*)d_in[5];
    const float* beta  = (const float*)d_in[6];
    float* ws  = (float*)d_ws;
    float* out = (float*)d_out;

    zero_kernel<<<34, 256, 0, stream>>>(ws);
    projmfma_kernel<<<dim3(32, 16), 256, 0, stream>>>(x, Wq, Wk, Wv, ws, out);
    qq_kernel<<<dim3(64, 16), 256, 0, stream>>>(out, ws);
    bnstat_kernel<<<16, 128, 0, stream>>>(Wout, ws);
    out_kernel<<<dim3(64, 16), 256, 0, stream>>>(out, ws, gamma, beta, out);
}